// Round 2
// baseline (227.896 us; speedup 1.0000x reference)
//
#include <hip/hip_runtime.h>

// GaussianModel covariance: cov = R(q_normalized) * diag(exp(2s)) * R^T per point.
// f32 in, f32 out. Traffic: 28 B read + 36 B write per point, N=4e6 -> 256 MB,
// floor ~41 us @ 6.29 TB/s mixed R/W (m13).
//
// R7 = R6 (barrier-free wave-synchronous restructure) with two fixes:
//  FIX 1: in_sizes[] is an f32 ELEMENT count (R0 passed with /4 -> n=4e6).
//         R6's "/16" gave n=1e6 -> 3/4 of output unwritten. Restored /4.
//  FIX 2: the wave-local transpose fence is now an explicit
//         asm volatile("s_waitcnt lgkmcnt(0)" ::: "memory") -- a real compiler
//         memory fence (LDS reads can't hoist above it) + hardware drain of the
//         LDS writes, independent of in-order-pipe assumptions.
//
// Structure (from R6):
//  1. Thread t owns CONSECUTIVE points base+2t, base+2t+1 -> each wave owns a
//     contiguous 128-point slab -> contiguous 4608 B out region per wave.
//  2. sca: NO LDS staging. 12*p0 is 8B-aligned -> 3x dwordx2 direct loads.
//  3. Output transpose is WAVE-LOCAL in a private 1152-float LDS slice; no
//     __syncthreads anywhere -> waves are independent pipelines, fully
//     overlappable across the 32 resident waves.
//  4. Nontemporal v4f stores for the 144 MB output stream.
// LDS 18432 B -> 8 blocks/CU; occupancy 32 waves/CU.
// Prediction: kernel ~51 -> ~44-47 us, dur_us 227 -> ~218-222. Neutral => roofline.

#define TPB 256
#define PPB 512   // points per block (2 consecutive per thread)

typedef float v4f __attribute__((ext_vector_type(4)));
typedef float v2f __attribute__((ext_vector_type(2)));

static __device__ __forceinline__ void cov_point(
    float w, float x, float y, float z,
    float s0, float s1, float s2, float c[9])
{
    float inv = rsqrtf(w * w + x * x + y * y + z * z);
    w *= inv; x *= inv; y *= inv; z *= inv;

    float r00 = 1.f - 2.f * (y * y + z * z);
    float r01 = 2.f * (x * y - w * z);
    float r02 = 2.f * (x * z + w * y);
    float r10 = 2.f * (x * y + w * z);
    float r11 = 1.f - 2.f * (x * x + z * z);
    float r12 = 2.f * (y * z - w * x);
    float r20 = 2.f * (x * z - w * y);
    float r21 = 2.f * (y * z + w * x);
    float r22 = 1.f - 2.f * (x * x + y * y);

    float t0 = __expf(2.f * s0);
    float t1 = __expf(2.f * s1);
    float t2 = __expf(2.f * s2);

    c[0] = r00 * r00 * t0 + r01 * r01 * t1 + r02 * r02 * t2;
    c[1] = r00 * r10 * t0 + r01 * r11 * t1 + r02 * r12 * t2;
    c[2] = r00 * r20 * t0 + r01 * r21 * t1 + r02 * r22 * t2;
    c[3] = c[1];
    c[4] = r10 * r10 * t0 + r11 * r11 * t1 + r12 * r12 * t2;
    c[5] = r10 * r20 * t0 + r11 * r21 * t1 + r12 * r22 * t2;
    c[6] = c[2];
    c[7] = c[5];
    c[8] = r20 * r20 * t0 + r21 * r21 * t1 + r22 * r22 * t2;
}

__global__ __launch_bounds__(TPB) void gaussian_cov_kernel(
    const float4* __restrict__ rot4,   // (N,4) f32 = N float4, lane-aligned
    const v2f*   __restrict__ sca2,    // (N,3) f32 viewed as float2 (8B-aligned)
    const float* __restrict__ sca_f,   // scalar view for odd remainder
    v4f* __restrict__ out4,            // (N,9) f32 viewed as v4f (block-aligned)
    float* __restrict__ out_f,         // scalar view for remainder
    int n)
{
    // Per-wave private slices: wave w owns lds[w*1152 .. w*1152+1151].
    __shared__ float lds[TPB * 18];    // 18432 B

    const int tid  = threadIdx.x;
    const int lane = tid & 63;
    const int wid  = tid >> 6;
    const int base = blockIdx.x * PPB;
    const int n_pt = min(PPB, n - base);     // 512, or partial in last block

    const int  rp0 = 2 * tid;                 // relative point index
    const int  p0  = base + rp0;
    const bool a0  = (rp0     < n_pt);
    const bool a1  = (rp0 + 1 < n_pt);

    // ---- direct loads: rot as float4, sca as 3x float2 (byte 12*p0, 8-aligned) ----
    float4 qa, qb;
    v2f sA, sB, sC;
    if (a1) {
        qa = rot4[p0];
        qb = rot4[p0 + 1];
        const v2f* g = sca2 + ((3 * (size_t)base) >> 1) + 3 * (size_t)tid;
        sA = g[0]; sB = g[1]; sC = g[2];
    } else if (a0) {
        qa = rot4[p0];
        const v2f* g = sca2 + ((3 * (size_t)base) >> 1) + 3 * (size_t)tid;
        sA = g[0];
        sB.x = sca_f[3 * (size_t)p0 + 2];     // avoid 4 B OOB past sca end
    }

    // ---- compute ----
    float c0[9], c1[9];
    if (a0) cov_point(qa.x, qa.y, qa.z, qa.w, sA.x, sA.y, sB.x, c0);
    if (a1) cov_point(qb.x, qb.y, qb.z, qb.w, sB.y, sC.x, sC.y, c1);

    // ---- wave-local transpose: lane-major IS point-major for consecutive pts ----
    float* lw = lds + wid * 1152;
    if (a0) {
        #pragma unroll
        for (int k = 0; k < 9; ++k) lw[18 * lane + k] = c0[k];
    }
    if (a1) {
        #pragma unroll
        for (int k = 0; k < 9; ++k) lw[18 * lane + 9 + k] = c1[k];
    }

    // Fence: "memory" clobber = compiler may not move the LDS reads above this;
    // lgkmcnt(0) = all LDS writes have landed. Wave-private region, so no
    // cross-wave sync is needed.
    asm volatile("s_waitcnt lgkmcnt(0)" ::: "memory");
    __builtin_amdgcn_wave_barrier();

    // ---- coalesced nontemporal copy-out of this wave's contiguous region ----
    const int n_w = min(max(n_pt - 128 * wid, 0), 128);  // points this wave owns
    if (n_w > 0) {
        const v4f*  lv   = (const v4f*)lw;
        const size_t ob  = 9 * (size_t)(base + 128 * wid);  // out float base
        v4f* gout = out4 + (ob >> 2);                        // ob % 4 == 0
        if (n_w == 128) {
            #pragma unroll
            for (int k = 0; k < 4; ++k)
                __builtin_nontemporal_store(lv[lane + 64 * k], &gout[lane + 64 * k]);
            if (lane < 32)
                __builtin_nontemporal_store(lv[256 + lane], &gout[256 + lane]);
        } else {
            const int nf = 9 * n_w;
            const int n4 = nf >> 2;
            for (int i = lane; i < n4; i += 64)
                __builtin_nontemporal_store(lv[i], &gout[i]);
            const int rem = nf & 3;
            if (lane < rem)
                out_f[ob + (size_t)(n4 << 2) + lane] = lw[(n4 << 2) + lane];
        }
    }
}

extern "C" void kernel_launch(void* const* d_in, const int* in_sizes, int n_in,
                              void* d_out, int out_size, void* d_ws, size_t ws_size,
                              hipStream_t stream) {
    const int n = in_sizes[0] / 4;   // in_sizes = f32 element count; (N,4) -> N points

    const float4* rot4 = (const float4*)d_in[0];
    const v2f*    sca2 = (const v2f*)d_in[1];
    const float*  scaf = (const float*)d_in[1];
    v4f*   out4 = (v4f*)d_out;
    float* outf = (float*)d_out;

    const int grid = (n + PPB - 1) / PPB;
    gaussian_cov_kernel<<<grid, TPB, 0, stream>>>(rot4, sca2, scaf, out4, outf, n);
}